// Round 1
// baseline (1721.301 us; speedup 1.0000x reference)
//
#include <hip/hip_runtime.h>
#include <hip/hip_bf16.h>

// Problem constants
#define S_LEN 2048
#define BB 32
#define EE 300
#define HH 256
#define VV 50000
#define GG 5

typedef float f32x4 __attribute__((ext_vector_type(4)));
typedef __bf16 bf16x8 __attribute__((ext_vector_type(8)));
typedef int i32x4 __attribute__((ext_vector_type(4)));

// ---------- helpers ----------
__device__ __forceinline__ unsigned short f2bf(float f) {
    unsigned int u = __builtin_bit_cast(unsigned int, f);
    u = u + 0x7fffu + ((u >> 16) & 1u);   // RNE
    return (unsigned short)(u >> 16);
}
__device__ __forceinline__ float bflo(unsigned int w) {
    return __builtin_bit_cast(float, w << 16);
}
__device__ __forceinline__ float bfhi(unsigned int w) {
    return __builtin_bit_cast(float, w & 0xffff0000u);
}
__device__ __forceinline__ float tanhf_fast(float x) {
    // tanh(x) = (e-1)/(e+1), e = exp(2x) = exp2(x * 2*log2(e))
    float e = __builtin_amdgcn_exp2f(x * 2.8853900817779268f);
    return (e - 1.0f) * __builtin_amdgcn_rcpf(e + 1.0f);
}

// ---------- K0: pack weights into MFMA-fragment-friendly bf16 layouts ----------
// Wp  [dir][kb(10)][kg(4)][j(256)][i(8)]  <- W_ih[j][e], e = kb*32+kg*8+i (zero-pad e>=300)
// Whp [dir][kb(8) ][kg(4)][j(256)][i(8)]  <- W_hh[j][k], k = kb*32+kg*8+i
// biasc[dir*256+j] = b_ih[j] + b_hh[j]
__global__ void k_pack(const float* __restrict__ Wih_f, const float* __restrict__ Whh_f,
                       const float* __restrict__ bih_f, const float* __restrict__ bhh_f,
                       const float* __restrict__ Wih_b, const float* __restrict__ Whh_b,
                       const float* __restrict__ bih_b, const float* __restrict__ bhh_b,
                       unsigned short* __restrict__ Wp, unsigned short* __restrict__ Whp,
                       float* __restrict__ biasc)
{
    int idx = blockIdx.x * 256 + threadIdx.x;
    if (idx < 163840) {
        int i = idx & 7, j = (idx >> 3) & 255, kg = (idx >> 11) & 3, kbd = idx >> 13;
        int kb = kbd % 10, dir = kbd / 10;
        int e = kb * 32 + kg * 8 + i;
        const float* W = dir ? Wih_b : Wih_f;
        float v = (e < EE) ? W[j * EE + e] : 0.0f;
        Wp[idx] = f2bf(v);
    } else if (idx < 163840 + 131072) {
        int x = idx - 163840;
        int i = x & 7, j = (x >> 3) & 255, kg = (x >> 11) & 3, kbd = x >> 13;
        int kb = kbd & 7, dir = kbd >> 3;
        int k = kb * 32 + kg * 8 + i;
        const float* W = dir ? Whh_b : Whh_f;
        Whp[x] = f2bf(W[j * HH + k]);
    } else if (idx < 163840 + 131072 + 512) {
        int x = idx - (163840 + 131072);
        int j = x & 255, dir = x >> 8;
        biasc[x] = dir ? (bih_b[j] + bhh_b[j]) : (bih_f[j] + bhh_f[j]);
    }
}

// ---------- K2: embedding gather + input projection (transposed MFMA GEMM) ----------
// Computes xq in the exact per-lane layout k_rnn consumes:
// xq[s][dir][half][w][lane][16 bf16]  where the 16 values are [t(4)][r(4)] =
//   xproj^T(j = w*64+t*16+(lane>>4)*4+r , b = half*16+(lane&15)) + bias[j]
__global__ __launch_bounds__(1024) void k_xproj(
    const int* __restrict__ tok, const float* __restrict__ emb,
    const unsigned short* __restrict__ Wp, const float* __restrict__ biasc,
    unsigned short* __restrict__ xq)
{
    __shared__ char xs[32 * 640];   // x[b][e(320)] bf16, XOR-swizzled rows
    int s = blockIdx.x;
    int tid = threadIdx.x;
    int lane = tid & 63, W16 = tid >> 6;

    // zero LDS (covers the e=300..319 zero pad)
    #pragma unroll
    for (int k = 0; k < 5; k++) ((int*)xs)[tid + k * 1024] = 0;
    __syncthreads();

    // gather: wave W16 loads batch rows 2*W16, 2*W16+1
    {
        int b0 = W16 * 2;
        for (int rr = 0; rr < 2; rr++) {
            int b = b0 + rr;
            int t = tok[b * S_LEN + s];
            const float* row = emb + (size_t)t * EE;
            int xorv = (b & 7) << 4;
            #pragma unroll
            for (int c = 0; c < 5; c++) {
                int e = c * 64 + lane;
                if (e < EE) {
                    *(unsigned short*)(xs + b * 640 + ((2 * e) ^ xorv)) = f2bf(row[e]);
                }
            }
        }
    }
    __syncthreads();

    int dir = W16 >> 3, w = (W16 >> 1) & 3, half = W16 & 1;
    int l15 = lane & 15, kg = lane >> 4;
    f32x4 acc[4] = {};
    int brow = half * 16 + l15;
    int bxor = (brow & 7) << 4;
    const char* xrow = xs + brow * 640;

    #pragma unroll
    for (int kb = 0; kb < 10; kb++) {
        bf16x8 xb = *(const bf16x8*)(xrow + ((kb * 64 + kg * 16) ^ bxor));
        #pragma unroll
        for (int t = 0; t < 4; t++) {
            int j = w * 64 + t * 16 + l15;
            bf16x8 wa = *(const bf16x8*)(Wp + (size_t)(((dir * 10 + kb) * 4 + kg) * 256 + j) * 8);
            acc[t] = __builtin_amdgcn_mfma_f32_16x16x32_bf16(wa, xb, acc[t], 0, 0, 0);
        }
    }

    // epilogue: add bias, pack to bf16, store 32B per lane
    unsigned int words[8];
    #pragma unroll
    for (int t = 0; t < 4; t++) {
        float v[4];
        #pragma unroll
        for (int r = 0; r < 4; r++) {
            int j = w * 64 + t * 16 + kg * 4 + r;
            v[r] = acc[t][r] + biasc[dir * 256 + j];
        }
        words[t * 2 + 0] = (unsigned int)f2bf(v[0]) | ((unsigned int)f2bf(v[1]) << 16);
        words[t * 2 + 1] = (unsigned int)f2bf(v[2]) | ((unsigned int)f2bf(v[3]) << 16);
    }
    size_t base = (size_t)s * 32768 + (size_t)((dir * 2 + half) * 4 + w) * 2048 + (size_t)lane * 32;
    *(i32x4*)((char*)xq + base) = *(i32x4*)&words[0];
    *(i32x4*)((char*)xq + base + 16) = *(i32x4*)&words[4];
}

// ---------- K3: the sequential recurrence (4 persistent workgroups) ----------
// block = (dir, batch-half). 4 waves; wave w owns output cols j in [w*64, w*64+64).
// W_hh fragments resident in VGPRs; h double-buffered in swizzled LDS; pool in regs.
__global__ __launch_bounds__(256, 1) void k_rnn(
    const unsigned short* __restrict__ xq,
    const unsigned short* __restrict__ Whp,
    float* __restrict__ pooled)
{
    __shared__ char hb[2][8192];   // h[b(16)][j(256)] bf16, XOR-swizzled rows
    int bid = blockIdx.x;
    int dir = bid >> 1, half = bid & 1;
    int tid = threadIdx.x;
    int lane = tid & 63, w = tid >> 6;
    int l15 = lane & 15, kg = lane >> 4;

    // resident W_hh fragments: A-operand, lane holds W[j = w*64+t*16+l15][k = kb*32+kg*8 ..+8]
    bf16x8 wf[4][8];
    #pragma unroll
    for (int t = 0; t < 4; t++)
        #pragma unroll
        for (int kb = 0; kb < 8; kb++) {
            int j = w * 64 + t * 16 + l15;
            wf[t][kb] = *(const bf16x8*)(Whp + (size_t)(((dir * 8 + kb) * 4 + kg) * 256 + j) * 8);
        }

    // zero h buffer 0 (h_0 = 0)
    *(i32x4*)(&hb[0][tid * 32]) = i32x4{0, 0, 0, 0};
    *(i32x4*)(&hb[0][tid * 32 + 16]) = i32x4{0, 0, 0, 0};

    f32x4 pool[4] = {};

    int roff[8];
    #pragma unroll
    for (int kb = 0; kb < 8; kb++)
        roff[kb] = l15 * 512 + ((kb * 64 + kg * 16) ^ ((lane & 7) << 4));
    int woff[4];
    #pragma unroll
    for (int t = 0; t < 4; t++)
        woff[t] = l15 * 512 + (((w * 64 + t * 16 + kg * 4) * 2) ^ ((lane & 7) << 4));

    size_t lanebase = (size_t)((dir * 2 + half) * 4 + w) * 2048 + (size_t)lane * 32;

    int s0 = dir ? (S_LEN - 1) : 0;
    i32x4 xn0 = *(const i32x4*)((const char*)xq + (size_t)s0 * 32768 + lanebase);
    i32x4 xn1 = *(const i32x4*)((const char*)xq + (size_t)s0 * 32768 + lanebase + 16);

    __syncthreads();

    for (int i = 0; i < S_LEN; i++) {
        const char* rbuf = hb[i & 1];
        char* wbuf = hb[(i + 1) & 1];

        // h fragments (B-operand): lane holds h[b = l15][k = kb*32+kg*8 ..+8]
        bf16x8 hf[8];
        #pragma unroll
        for (int kb = 0; kb < 8; kb++)
            hf[kb] = *(const bf16x8*)(rbuf + roff[kb]);

        // init acc from prefetched xproj (bf16 -> f32)
        unsigned int wd[8];
        *(i32x4*)&wd[0] = xn0;
        *(i32x4*)&wd[4] = xn1;
        f32x4 acc[4];
        #pragma unroll
        for (int t = 0; t < 4; t++) {
            acc[t][0] = bflo(wd[t * 2 + 0]);
            acc[t][1] = bfhi(wd[t * 2 + 0]);
            acc[t][2] = bflo(wd[t * 2 + 1]);
            acc[t][3] = bfhi(wd[t * 2 + 1]);
        }

        // prefetch next step's xproj (latency hidden under MFMA)
        int ni = (i + 1 < S_LEN) ? (i + 1) : i;
        int sn = dir ? (S_LEN - 1 - ni) : ni;
        xn0 = *(const i32x4*)((const char*)xq + (size_t)sn * 32768 + lanebase);
        xn1 = *(const i32x4*)((const char*)xq + (size_t)sn * 32768 + lanebase + 16);

        // D[j][b] += sum_k W[j,k] * h[b,k]
        #pragma unroll
        for (int kb = 0; kb < 8; kb++)
            #pragma unroll
            for (int t = 0; t < 4; t++)
                acc[t] = __builtin_amdgcn_mfma_f32_16x16x32_bf16(wf[t][kb], hf[kb], acc[t], 0, 0, 0);

        // tanh, accumulate pool, pack 4 consecutive-j bf16, write 8B to LDS
        #pragma unroll
        for (int t = 0; t < 4; t++) {
            float h0 = tanhf_fast(acc[t][0]);
            float h1 = tanhf_fast(acc[t][1]);
            float h2 = tanhf_fast(acc[t][2]);
            float h3 = tanhf_fast(acc[t][3]);
            pool[t][0] += h0; pool[t][1] += h1; pool[t][2] += h2; pool[t][3] += h3;
            unsigned int lo = (unsigned int)f2bf(h0) | ((unsigned int)f2bf(h1) << 16);
            unsigned int hi = (unsigned int)f2bf(h2) | ((unsigned int)f2bf(h3) << 16);
            *(uint2*)(wbuf + woff[t]) = make_uint2(lo, hi);
        }
        __syncthreads();
    }

    // write pooled sums (mean division happens in k_head)
    #pragma unroll
    for (int t = 0; t < 4; t++)
        #pragma unroll
        for (int r = 0; r < 4; r++) {
            int j = w * 64 + t * 16 + kg * 4 + r;
            int b = half * 16 + l15;
            pooled[b * 512 + dir * 256 + j] = pool[t][r];
        }
}

// ---------- K4: head: tanh(mean) @ fc_W^T + fc_b ----------
__global__ __launch_bounds__(64) void k_head(
    const float* __restrict__ pooled, const float* __restrict__ fcW,
    const float* __restrict__ fcb, float* __restrict__ out)
{
    int b = blockIdx.x;
    int lane = threadIdx.x;
    float p[GG] = {0, 0, 0, 0, 0};
    for (int jj = lane; jj < 512; jj += 64) {
        float a = tanhf_fast(pooled[b * 512 + jj] * (1.0f / 2048.0f));
        #pragma unroll
        for (int g = 0; g < GG; g++) p[g] += a * fcW[g * 512 + jj];
    }
    #pragma unroll
    for (int g = 0; g < GG; g++)
        #pragma unroll
        for (int off = 32; off; off >>= 1) p[g] += __shfl_xor(p[g], off);
    if (lane == 0) {
        #pragma unroll
        for (int g = 0; g < GG; g++) out[b * GG + g] = p[g] + fcb[g];
    }
}

// ---------- launcher ----------
extern "C" void kernel_launch(void* const* d_in, const int* in_sizes, int n_in,
                              void* d_out, int out_size, void* d_ws, size_t ws_size,
                              hipStream_t stream)
{
    const int* tok = (const int*)d_in[0];
    const float* emb = (const float*)d_in[1];
    const float* Wih_f = (const float*)d_in[2];
    const float* Whh_f = (const float*)d_in[3];
    const float* bih_f = (const float*)d_in[4];
    const float* bhh_f = (const float*)d_in[5];
    const float* Wih_b = (const float*)d_in[6];
    const float* Whh_b = (const float*)d_in[7];
    const float* bih_b = (const float*)d_in[8];
    const float* bhh_b = (const float*)d_in[9];
    const float* fcW = (const float*)d_in[10];
    const float* fcb = (const float*)d_in[11];
    float* out = (float*)d_out;

    char* ws = (char*)d_ws;
    unsigned short* xq   = (unsigned short*)(ws);                       // 67,108,864 B
    unsigned short* Wp   = (unsigned short*)(ws + 67108864);            //    327,680 B
    unsigned short* Whp  = (unsigned short*)(ws + 67108864 + 327680);   //    262,144 B
    float* biasc         = (float*)(ws + 67108864 + 327680 + 262144);   //      2,048 B
    float* pooled        = (float*)(ws + 67108864 + 327680 + 262144 + 2048); // 65,536 B

    hipLaunchKernelGGL(k_pack, dim3(1154), dim3(256), 0, stream,
                       Wih_f, Whh_f, bih_f, bhh_f, Wih_b, Whh_b, bih_b, bhh_b,
                       Wp, Whp, biasc);
    hipLaunchKernelGGL(k_xproj, dim3(2048), dim3(1024), 0, stream,
                       tok, emb, Wp, biasc, xq);
    hipLaunchKernelGGL(k_rnn, dim3(4), dim3(256), 0, stream, xq, Whp, pooled);
    hipLaunchKernelGGL(k_head, dim3(32), dim3(64), 0, stream, pooled, fcW, fcb, out);
}

// Round 2
// 1514.323 us; speedup vs baseline: 1.1367x; 1.1367x over previous
//
#include <hip/hip_runtime.h>
#include <hip/hip_bf16.h>

// Problem constants
#define S_LEN 2048
#define BB 32
#define EE 300
#define HH 256
#define VV 50000
#define GG 5

typedef float f32x4 __attribute__((ext_vector_type(4)));
typedef __bf16 bf16x8 __attribute__((ext_vector_type(8)));
typedef int i32x4 __attribute__((ext_vector_type(4)));

// ---------- helpers ----------
__device__ __forceinline__ unsigned short f2bf(float f) {
    unsigned int u = __builtin_bit_cast(unsigned int, f);
    u = u + 0x7fffu + ((u >> 16) & 1u);   // RNE
    return (unsigned short)(u >> 16);
}
__device__ __forceinline__ float bflo(unsigned int w) {
    return __builtin_bit_cast(float, w << 16);
}
__device__ __forceinline__ float bfhi(unsigned int w) {
    return __builtin_bit_cast(float, w & 0xffff0000u);
}
__device__ __forceinline__ float tanhf_fast(float x) {
    // tanh(x) = (e-1)/(e+1), e = exp(2x) = exp2(x * 2*log2(e))
    float e = __builtin_amdgcn_exp2f(x * 2.8853900817779268f);
    return (e - 1.0f) * __builtin_amdgcn_rcpf(e + 1.0f);
}
// pack two f32 -> dword of 2 bf16 (RNE), single instruction
__device__ __forceinline__ unsigned int cvt_pk_bf16(float lo, float hi) {
    unsigned int r;
    asm("v_cvt_pk_bf16_f32 %0, %1, %2" : "=v"(r) : "v"(lo), "v"(hi));
    return r;
}

// ---------- K0: pack weights into MFMA-fragment-friendly bf16 layouts ----------
// Wp  [dir][kb(10)][kg(4)][j(256)][i(8)]  <- W_ih[j][e], e = kb*32+kg*8+i (zero-pad e>=300)
// Whp [dir][kb(8) ][kg(4)][j(256)][i(8)]  <- W_hh[j][k], k = kb*32+kg*8+i
// biasc[dir*256+j] = b_ih[j] + b_hh[j]
__global__ void k_pack(const float* __restrict__ Wih_f, const float* __restrict__ Whh_f,
                       const float* __restrict__ bih_f, const float* __restrict__ bhh_f,
                       const float* __restrict__ Wih_b, const float* __restrict__ Whh_b,
                       const float* __restrict__ bih_b, const float* __restrict__ bhh_b,
                       unsigned short* __restrict__ Wp, unsigned short* __restrict__ Whp,
                       float* __restrict__ biasc)
{
    int idx = blockIdx.x * 256 + threadIdx.x;
    if (idx < 163840) {
        int i = idx & 7, j = (idx >> 3) & 255, kg = (idx >> 11) & 3, kbd = idx >> 13;
        int kb = kbd % 10, dir = kbd / 10;
        int e = kb * 32 + kg * 8 + i;
        const float* W = dir ? Wih_b : Wih_f;
        float v = (e < EE) ? W[j * EE + e] : 0.0f;
        Wp[idx] = f2bf(v);
    } else if (idx < 163840 + 131072) {
        int x = idx - 163840;
        int i = x & 7, j = (x >> 3) & 255, kg = (x >> 11) & 3, kbd = x >> 13;
        int kb = kbd & 7, dir = kbd >> 3;
        int k = kb * 32 + kg * 8 + i;
        const float* W = dir ? Whh_b : Whh_f;
        Whp[x] = f2bf(W[j * HH + k]);
    } else if (idx < 163840 + 131072 + 512) {
        int x = idx - (163840 + 131072);
        int j = x & 255, dir = x >> 8;
        biasc[x] = dir ? (bih_b[j] + bhh_b[j]) : (bih_f[j] + bhh_f[j]);
    }
}

// ---------- K2: embedding gather + input projection (transposed MFMA GEMM) ----------
// xq[s][dir][half][w][lane][16 bf16]: [t(4)][r(4)] =
//   xproj^T(j = w*64+t*16+(lane>>4)*4+r , b = half*16+(lane&15)) + bias[j]
__global__ __launch_bounds__(1024) void k_xproj(
    const int* __restrict__ tok, const float* __restrict__ emb,
    const unsigned short* __restrict__ Wp, const float* __restrict__ biasc,
    unsigned short* __restrict__ xq)
{
    __shared__ char xs[32 * 640];   // x[b][e(320)] bf16, XOR-swizzled rows
    int s = blockIdx.x;
    int tid = threadIdx.x;
    int lane = tid & 63, W16 = tid >> 6;

    #pragma unroll
    for (int k = 0; k < 5; k++) ((int*)xs)[tid + k * 1024] = 0;
    __syncthreads();

    {
        int b0 = W16 * 2;
        for (int rr = 0; rr < 2; rr++) {
            int b = b0 + rr;
            int t = tok[b * S_LEN + s];
            const float* row = emb + (size_t)t * EE;
            int xorv = (b & 7) << 4;
            #pragma unroll
            for (int c = 0; c < 5; c++) {
                int e = c * 64 + lane;
                if (e < EE) {
                    *(unsigned short*)(xs + b * 640 + ((2 * e) ^ xorv)) = f2bf(row[e]);
                }
            }
        }
    }
    __syncthreads();

    int dir = W16 >> 3, w = (W16 >> 1) & 3, half = W16 & 1;
    int l15 = lane & 15, kg = lane >> 4;
    f32x4 acc[4] = {};
    int brow = half * 16 + l15;
    int bxor = (brow & 7) << 4;
    const char* xrow = xs + brow * 640;

    #pragma unroll
    for (int kb = 0; kb < 10; kb++) {
        bf16x8 xb = *(const bf16x8*)(xrow + ((kb * 64 + kg * 16) ^ bxor));
        #pragma unroll
        for (int t = 0; t < 4; t++) {
            int j = w * 64 + t * 16 + l15;
            bf16x8 wa = *(const bf16x8*)(Wp + (size_t)(((dir * 10 + kb) * 4 + kg) * 256 + j) * 8);
            acc[t] = __builtin_amdgcn_mfma_f32_16x16x32_bf16(wa, xb, acc[t], 0, 0, 0);
        }
    }

    unsigned int words[8];
    #pragma unroll
    for (int t = 0; t < 4; t++) {
        float v[4];
        #pragma unroll
        for (int r = 0; r < 4; r++) {
            int j = w * 64 + t * 16 + kg * 4 + r;
            v[r] = acc[t][r] + biasc[dir * 256 + j];
        }
        words[t * 2 + 0] = cvt_pk_bf16(v[0], v[1]);
        words[t * 2 + 1] = cvt_pk_bf16(v[2], v[3]);
    }
    size_t base = (size_t)s * 32768 + (size_t)((dir * 2 + half) * 4 + w) * 2048 + (size_t)lane * 32;
    *(i32x4*)((char*)xq + base) = *(i32x4*)&words[0];
    *(i32x4*)((char*)xq + base + 16) = *(i32x4*)&words[4];
}

// ---------- K3: the sequential recurrence (4 persistent workgroups) ----------
// block = (dir, batch-half). 4 waves; wave w owns output cols j in [w*64, w*64+64).
// W_hh fragments resident in VGPRs; h double-buffered in swizzled LDS; pool in regs.
// Raw barrier (lgkmcnt-only drain) keeps the xq prefetch in flight across steps.
__global__ __launch_bounds__(256, 1) void k_rnn(
    const unsigned short* __restrict__ xq,
    const unsigned short* __restrict__ Whp,
    float* __restrict__ pooled)
{
    __shared__ char hb0[8192];   // h[b(16)][j(256)] bf16, XOR-swizzled rows
    __shared__ char hb1[8192];
    int bid = blockIdx.x;
    int dir = bid >> 1, half = bid & 1;
    int tid = threadIdx.x;
    int lane = tid & 63, w = tid >> 6;
    int l15 = lane & 15, kg = lane >> 4;

    // resident W_hh fragments: A-operand, lane holds W[j = w*64+t*16+l15][k = kb*32+kg*8 ..+8]
    bf16x8 wf[4][8];
    #pragma unroll
    for (int t = 0; t < 4; t++)
        #pragma unroll
        for (int kb = 0; kb < 8; kb++) {
            int j = w * 64 + t * 16 + l15;
            wf[t][kb] = *(const bf16x8*)(Whp + (size_t)(((dir * 8 + kb) * 4 + kg) * 256 + j) * 8);
        }

    // zero h buffer 0 (h_0 = 0)
    *(i32x4*)(&hb0[tid * 32]) = i32x4{0, 0, 0, 0};
    *(i32x4*)(&hb0[tid * 32 + 16]) = i32x4{0, 0, 0, 0};

    f32x4 pool[4] = {};

    int roff[8];
    #pragma unroll
    for (int kb = 0; kb < 8; kb++)
        roff[kb] = l15 * 512 + ((kb * 64 + kg * 16) ^ ((lane & 7) << 4));
    int woff[4];
    #pragma unroll
    for (int t = 0; t < 4; t++)
        woff[t] = l15 * 512 + (((w * 64 + t * 16 + kg * 4) * 2) ^ ((lane & 7) << 4));

    size_t lanebase = (size_t)((dir * 2 + half) * 4 + w) * 2048 + (size_t)lane * 32;
    ptrdiff_t sdelta = dir ? -(ptrdiff_t)32768 : (ptrdiff_t)32768;
    int s0 = dir ? (S_LEN - 1) : 0;

    const char* xqp = (const char*)xq + (size_t)s0 * 32768 + lanebase;
    i32x4 xn0 = *(const i32x4*)(xqp);
    i32x4 xn1 = *(const i32x4*)(xqp + 16);
    xqp += sdelta;   // now points at step 1's data

    __syncthreads();

#define STEP(RB, WB, DO_PF)                                                          \
    {                                                                                \
        bf16x8 hf[8];                                                                \
        _Pragma("unroll")                                                            \
        for (int kb = 0; kb < 8; kb++)                                               \
            hf[kb] = *(const bf16x8*)((RB) + roff[kb]);                              \
        unsigned int wd[8];                                                          \
        *(i32x4*)&wd[0] = xn0;                                                       \
        *(i32x4*)&wd[4] = xn1;                                                       \
        if (DO_PF) {                                                                 \
            xn0 = *(const i32x4*)(xqp);                                              \
            xn1 = *(const i32x4*)(xqp + 16);                                         \
            xqp += sdelta;                                                           \
        }                                                                            \
        f32x4 acc[4];                                                                \
        _Pragma("unroll")                                                            \
        for (int t = 0; t < 4; t++) {                                                \
            acc[t][0] = bflo(wd[t * 2 + 0]);                                         \
            acc[t][1] = bfhi(wd[t * 2 + 0]);                                         \
            acc[t][2] = bflo(wd[t * 2 + 1]);                                         \
            acc[t][3] = bfhi(wd[t * 2 + 1]);                                         \
        }                                                                            \
        _Pragma("unroll")                                                            \
        for (int kb = 0; kb < 8; kb++)                                               \
            _Pragma("unroll")                                                        \
            for (int t = 0; t < 4; t++)                                              \
                acc[t] = __builtin_amdgcn_mfma_f32_16x16x32_bf16(wf[t][kb], hf[kb],  \
                                                                 acc[t], 0, 0, 0);   \
        _Pragma("unroll")                                                            \
        for (int t = 0; t < 4; t++) {                                                \
            float h0 = tanhf_fast(acc[t][0]);                                        \
            float h1 = tanhf_fast(acc[t][1]);                                        \
            float h2 = tanhf_fast(acc[t][2]);                                        \
            float h3 = tanhf_fast(acc[t][3]);                                        \
            pool[t][0] += h0; pool[t][1] += h1;                                      \
            pool[t][2] += h2; pool[t][3] += h3;                                      \
            unsigned int lo = cvt_pk_bf16(h0, h1);                                   \
            unsigned int hi = cvt_pk_bf16(h2, h3);                                   \
            *(uint2*)((WB) + woff[t]) = make_uint2(lo, hi);                          \
        }                                                                            \
        asm volatile("s_waitcnt lgkmcnt(0)" ::: "memory");                           \
        __builtin_amdgcn_s_barrier();                                                \
    }

    // steps 0 .. S_LEN-3 (unrolled by 2, always prefetch: target step <= S_LEN-2)
    for (int i = 0; i < S_LEN - 2; i += 2) {
        STEP(hb0, hb1, 1)
        STEP(hb1, hb0, 1)
    }
    // step S_LEN-2: prefetch step S_LEN-1 (valid); step S_LEN-1: no prefetch
    STEP(hb0, hb1, 1)
    STEP(hb1, hb0, 0)
#undef STEP

    // write pooled sums (mean division happens in k_head)
    #pragma unroll
    for (int t = 0; t < 4; t++)
        #pragma unroll
        for (int r = 0; r < 4; r++) {
            int j = w * 64 + t * 16 + kg * 4 + r;
            int b = half * 16 + l15;
            pooled[b * 512 + dir * 256 + j] = pool[t][r];
        }
}

// ---------- K4: head: tanh(mean) @ fc_W^T + fc_b ----------
__global__ __launch_bounds__(64) void k_head(
    const float* __restrict__ pooled, const float* __restrict__ fcW,
    const float* __restrict__ fcb, float* __restrict__ out)
{
    int b = blockIdx.x;
    int lane = threadIdx.x;
    float p[GG] = {0, 0, 0, 0, 0};
    for (int jj = lane; jj < 512; jj += 64) {
        float a = tanhf_fast(pooled[b * 512 + jj] * (1.0f / 2048.0f));
        #pragma unroll
        for (int g = 0; g < GG; g++) p[g] += a * fcW[g * 512 + jj];
    }
    #pragma unroll
    for (int g = 0; g < GG; g++)
        #pragma unroll
        for (int off = 32; off; off >>= 1) p[g] += __shfl_xor(p[g], off);
    if (lane == 0) {
        #pragma unroll
        for (int g = 0; g < GG; g++) out[b * GG + g] = p[g] + fcb[g];
    }
}

// ---------- launcher ----------
extern "C" void kernel_launch(void* const* d_in, const int* in_sizes, int n_in,
                              void* d_out, int out_size, void* d_ws, size_t ws_size,
                              hipStream_t stream)
{
    const int* tok = (const int*)d_in[0];
    const float* emb = (const float*)d_in[1];
    const float* Wih_f = (const float*)d_in[2];
    const float* Whh_f = (const float*)d_in[3];
    const float* bih_f = (const float*)d_in[4];
    const float* bhh_f = (const float*)d_in[5];
    const float* Wih_b = (const float*)d_in[6];
    const float* Whh_b = (const float*)d_in[7];
    const float* bih_b = (const float*)d_in[8];
    const float* bhh_b = (const float*)d_in[9];
    const float* fcW = (const float*)d_in[10];
    const float* fcb = (const float*)d_in[11];
    float* out = (float*)d_out;

    char* ws = (char*)d_ws;
    unsigned short* xq   = (unsigned short*)(ws);                       // 67,108,864 B
    unsigned short* Wp   = (unsigned short*)(ws + 67108864);            //    327,680 B
    unsigned short* Whp  = (unsigned short*)(ws + 67108864 + 327680);   //    262,144 B
    float* biasc         = (float*)(ws + 67108864 + 327680 + 262144);   //      2,048 B
    float* pooled        = (float*)(ws + 67108864 + 327680 + 262144 + 2048); // 65,536 B

    hipLaunchKernelGGL(k_pack, dim3(1154), dim3(256), 0, stream,
                       Wih_f, Whh_f, bih_f, bhh_f, Wih_b, Whh_b, bih_b, bhh_b,
                       Wp, Whp, biasc);
    hipLaunchKernelGGL(k_xproj, dim3(2048), dim3(1024), 0, stream,
                       tok, emb, Wp, biasc, xq);
    hipLaunchKernelGGL(k_rnn, dim3(4), dim3(256), 0, stream, xq, Whp, pooled);
    hipLaunchKernelGGL(k_head, dim3(32), dim3(64), 0, stream, pooled, fcW, fcb, out);
}

// Round 3
// 1422.636 us; speedup vs baseline: 1.2099x; 1.0644x over previous
//
#include <hip/hip_runtime.h>
#include <hip/hip_bf16.h>

// Problem constants
#define S_LEN 2048
#define BB 32
#define EE 300
#define HH 256
#define VV 50000
#define GG 5

typedef float f32x4 __attribute__((ext_vector_type(4)));
typedef __bf16 bf16x8 __attribute__((ext_vector_type(8)));
typedef int i32x4 __attribute__((ext_vector_type(4)));

// ---------- helpers ----------
__device__ __forceinline__ unsigned short f2bf(float f) {
    unsigned int u = __builtin_bit_cast(unsigned int, f);
    u = u + 0x7fffu + ((u >> 16) & 1u);   // RNE
    return (unsigned short)(u >> 16);
}
__device__ __forceinline__ float bflo(unsigned int w) {
    return __builtin_bit_cast(float, w << 16);
}
__device__ __forceinline__ float bfhi(unsigned int w) {
    return __builtin_bit_cast(float, w & 0xffff0000u);
}
__device__ __forceinline__ float tanhf_fast(float x) {
    // tanh(x) = 1 - 2/(e+1), e = exp2(x * 2*log2(e))  [5 ops: 3 VALU + 2 trans]
    float e = __builtin_amdgcn_exp2f(x * 2.8853900817779268f);
    float r = __builtin_amdgcn_rcpf(e + 1.0f);
    return __builtin_fmaf(-2.0f, r, 1.0f);
}
// pack two f32 -> dword of 2 bf16 (RNE), single instruction
__device__ __forceinline__ unsigned int cvt_pk_bf16(float lo, float hi) {
    unsigned int r;
    asm("v_cvt_pk_bf16_f32 %0, %1, %2" : "=v"(r) : "v"(lo), "v"(hi));
    return r;
}

// ---------- K0: pack weights into MFMA-fragment-friendly bf16 layouts ----------
// Wp  [dir][kb(10)][kg(4)][j(256)][i(8)]  <- W_ih[j][e], e = kb*32+kg*8+i (zero-pad e>=300)
// Whp [dir][kb(8) ][kg(4)][j(256)][i(8)]  <- W_hh[j][k], k = kb*32+kg*8+i
// biasc[dir*256+j] = b_ih[j] + b_hh[j]
__global__ void k_pack(const float* __restrict__ Wih_f, const float* __restrict__ Whh_f,
                       const float* __restrict__ bih_f, const float* __restrict__ bhh_f,
                       const float* __restrict__ Wih_b, const float* __restrict__ Whh_b,
                       const float* __restrict__ bih_b, const float* __restrict__ bhh_b,
                       unsigned short* __restrict__ Wp, unsigned short* __restrict__ Whp,
                       float* __restrict__ biasc)
{
    int idx = blockIdx.x * 256 + threadIdx.x;
    if (idx < 163840) {
        int i = idx & 7, j = (idx >> 3) & 255, kg = (idx >> 11) & 3, kbd = idx >> 13;
        int kb = kbd % 10, dir = kbd / 10;
        int e = kb * 32 + kg * 8 + i;
        const float* W = dir ? Wih_b : Wih_f;
        float v = (e < EE) ? W[j * EE + e] : 0.0f;
        Wp[idx] = f2bf(v);
    } else if (idx < 163840 + 131072) {
        int x = idx - 163840;
        int i = x & 7, j = (x >> 3) & 255, kg = (x >> 11) & 3, kbd = x >> 13;
        int kb = kbd & 7, dir = kbd >> 3;
        int k = kb * 32 + kg * 8 + i;
        const float* W = dir ? Whh_b : Whh_f;
        Whp[x] = f2bf(W[j * HH + k]);
    } else if (idx < 163840 + 131072 + 512) {
        int x = idx - (163840 + 131072);
        int j = x & 255, dir = x >> 8;
        biasc[x] = dir ? (bih_b[j] + bhh_b[j]) : (bih_f[j] + bhh_f[j]);
    }
}

// ---------- K2: embedding gather + input projection (transposed MFMA GEMM) ----------
// xq[s][dir][half][w4][lane][16 bf16]: [t(4)][r(4)] =
//   xproj^T(j = w4*64+t*16+(lane>>4)*4+r , b = half*16+(lane&15)) + bias[j]
__global__ __launch_bounds__(1024) void k_xproj(
    const int* __restrict__ tok, const float* __restrict__ emb,
    const unsigned short* __restrict__ Wp, const float* __restrict__ biasc,
    unsigned short* __restrict__ xq)
{
    __shared__ char xs[32 * 640];   // x[b][e(320)] bf16, XOR-swizzled rows
    int s = blockIdx.x;
    int tid = threadIdx.x;
    int lane = tid & 63, W16 = tid >> 6;

    #pragma unroll
    for (int k = 0; k < 5; k++) ((int*)xs)[tid + k * 1024] = 0;
    __syncthreads();

    {
        int b0 = W16 * 2;
        for (int rr = 0; rr < 2; rr++) {
            int b = b0 + rr;
            int t = tok[b * S_LEN + s];
            const float* row = emb + (size_t)t * EE;
            int xorv = (b & 7) << 4;
            #pragma unroll
            for (int c = 0; c < 5; c++) {
                int e = c * 64 + lane;
                if (e < EE) {
                    *(unsigned short*)(xs + b * 640 + ((2 * e) ^ xorv)) = f2bf(row[e]);
                }
            }
        }
    }
    __syncthreads();

    int dir = W16 >> 3, w = (W16 >> 1) & 3, half = W16 & 1;
    int l15 = lane & 15, kg = lane >> 4;
    f32x4 acc[4] = {};
    int brow = half * 16 + l15;
    int bxor = (brow & 7) << 4;
    const char* xrow = xs + brow * 640;

    #pragma unroll
    for (int kb = 0; kb < 10; kb++) {
        bf16x8 xb = *(const bf16x8*)(xrow + ((kb * 64 + kg * 16) ^ bxor));
        #pragma unroll
        for (int t = 0; t < 4; t++) {
            int j = w * 64 + t * 16 + l15;
            bf16x8 wa = *(const bf16x8*)(Wp + (size_t)(((dir * 10 + kb) * 4 + kg) * 256 + j) * 8);
            acc[t] = __builtin_amdgcn_mfma_f32_16x16x32_bf16(wa, xb, acc[t], 0, 0, 0);
        }
    }

    unsigned int words[8];
    #pragma unroll
    for (int t = 0; t < 4; t++) {
        float v[4];
        #pragma unroll
        for (int r = 0; r < 4; r++) {
            int j = w * 64 + t * 16 + kg * 4 + r;
            v[r] = acc[t][r] + biasc[dir * 256 + j];
        }
        words[t * 2 + 0] = cvt_pk_bf16(v[0], v[1]);
        words[t * 2 + 1] = cvt_pk_bf16(v[2], v[3]);
    }
    size_t base = (size_t)s * 32768 + (size_t)((dir * 2 + half) * 4 + w) * 2048 + (size_t)lane * 32;
    *(i32x4*)((char*)xq + base) = *(i32x4*)&words[0];
    *(i32x4*)((char*)xq + base + 16) = *(i32x4*)&words[4];
}

// ---------- K3: the sequential recurrence (4 persistent workgroups, 8 waves each) ----------
// block = (dir, batch-half). 8 waves -> 2 waves/SIMD for latency hiding.
// Wave w owns j in [w*32, w*32+32) (2 MFMA chains). W_hh fragments resident in VGPRs;
// h double-buffered in swizzled LDS; raw barrier keeps xq prefetch in flight.
__global__ __launch_bounds__(512, 2) void k_rnn(
    const unsigned short* __restrict__ xq,
    const unsigned short* __restrict__ Whp,
    float* __restrict__ pooled)
{
    __shared__ char hb0[8192];   // h[b(16)][j(256)] bf16, XOR-swizzled rows
    __shared__ char hb1[8192];
    int bid = blockIdx.x;
    int dir = bid >> 1, half = bid & 1;
    int tid = threadIdx.x;
    int lane = tid & 63, w = tid >> 6;          // w in 0..7
    int l15 = lane & 15, kg = lane >> 4;

    // resident W_hh fragments: A-operand, lane holds W[j = w*32+t*16+l15][k = kb*32+kg*8 ..+8]
    bf16x8 wf[2][8];
    #pragma unroll
    for (int t = 0; t < 2; t++)
        #pragma unroll
        for (int kb = 0; kb < 8; kb++) {
            int j = w * 32 + t * 16 + l15;
            wf[t][kb] = *(const bf16x8*)(Whp + (size_t)(((dir * 8 + kb) * 4 + kg) * 256 + j) * 8);
        }

    // zero h buffer 0 (h_0 = 0): 512 threads x 16B = 8192B
    *(i32x4*)(&hb0[tid * 16]) = i32x4{0, 0, 0, 0};

    f32x4 pool[2] = {};

    int roff[8];
    #pragma unroll
    for (int kb = 0; kb < 8; kb++)
        roff[kb] = l15 * 512 + ((kb * 64 + kg * 16) ^ ((l15 & 7) << 4));
    int woff[2];
    #pragma unroll
    for (int t = 0; t < 2; t++)
        woff[t] = l15 * 512 + (((w * 32 + t * 16 + kg * 4) * 2) ^ ((l15 & 7) << 4));

    // xq record: 32B per (w4, lane); wave w reads 16B half (w&1)
    size_t lanebase = (size_t)((dir * 2 + half) * 4 + (w >> 1)) * 2048
                    + (size_t)lane * 32 + (size_t)(w & 1) * 16;
    ptrdiff_t sdelta = dir ? -(ptrdiff_t)32768 : (ptrdiff_t)32768;
    int s0 = dir ? (S_LEN - 1) : 0;

    const char* xqp = (const char*)xq + (size_t)s0 * 32768 + lanebase;
    i32x4 xn = *(const i32x4*)(xqp);
    xqp += sdelta;   // now points at step 1's data

    __syncthreads();

#define STEP(RB, WB, DO_PF)                                                          \
    {                                                                                \
        bf16x8 hf[8];                                                                \
        _Pragma("unroll")                                                            \
        for (int kb = 0; kb < 8; kb++)                                               \
            hf[kb] = *(const bf16x8*)((RB) + roff[kb]);                              \
        unsigned int wd[4];                                                          \
        *(i32x4*)&wd[0] = xn;                                                        \
        if (DO_PF) {                                                                 \
            xn = *(const i32x4*)(xqp);                                               \
            xqp += sdelta;                                                           \
        }                                                                            \
        f32x4 acc[2];                                                                \
        _Pragma("unroll")                                                            \
        for (int t = 0; t < 2; t++) {                                                \
            acc[t][0] = bflo(wd[t * 2 + 0]);                                         \
            acc[t][1] = bfhi(wd[t * 2 + 0]);                                         \
            acc[t][2] = bflo(wd[t * 2 + 1]);                                         \
            acc[t][3] = bfhi(wd[t * 2 + 1]);                                         \
        }                                                                            \
        _Pragma("unroll")                                                            \
        for (int kb = 0; kb < 8; kb++)                                               \
            _Pragma("unroll")                                                        \
            for (int t = 0; t < 2; t++)                                              \
                acc[t] = __builtin_amdgcn_mfma_f32_16x16x32_bf16(wf[t][kb], hf[kb],  \
                                                                 acc[t], 0, 0, 0);   \
        _Pragma("unroll")                                                            \
        for (int t = 0; t < 2; t++) {                                                \
            float h0 = tanhf_fast(acc[t][0]);                                        \
            float h1 = tanhf_fast(acc[t][1]);                                        \
            float h2 = tanhf_fast(acc[t][2]);                                        \
            float h3 = tanhf_fast(acc[t][3]);                                        \
            pool[t][0] += h0; pool[t][1] += h1;                                      \
            pool[t][2] += h2; pool[t][3] += h3;                                      \
            unsigned int lo = cvt_pk_bf16(h0, h1);                                   \
            unsigned int hi = cvt_pk_bf16(h2, h3);                                   \
            *(uint2*)((WB) + woff[t]) = make_uint2(lo, hi);                          \
        }                                                                            \
        asm volatile("s_waitcnt lgkmcnt(0)" ::: "memory");                           \
        __builtin_amdgcn_s_barrier();                                                \
    }

    // steps 0 .. S_LEN-3 (unrolled by 2, always prefetch: target step <= S_LEN-2)
    for (int i = 0; i < S_LEN - 2; i += 2) {
        STEP(hb0, hb1, 1)
        STEP(hb1, hb0, 1)
    }
    // step S_LEN-2: prefetch step S_LEN-1 (valid); step S_LEN-1: no prefetch
    STEP(hb0, hb1, 1)
    STEP(hb1, hb0, 0)
#undef STEP

    // write pooled sums (mean division happens in k_head)
    #pragma unroll
    for (int t = 0; t < 2; t++)
        #pragma unroll
        for (int r = 0; r < 4; r++) {
            int j = w * 32 + t * 16 + kg * 4 + r;
            int b = half * 16 + l15;
            pooled[b * 512 + dir * 256 + j] = pool[t][r];
        }
}

// ---------- K4: head: tanh(mean) @ fc_W^T + fc_b ----------
__global__ __launch_bounds__(64) void k_head(
    const float* __restrict__ pooled, const float* __restrict__ fcW,
    const float* __restrict__ fcb, float* __restrict__ out)
{
    int b = blockIdx.x;
    int lane = threadIdx.x;
    float p[GG] = {0, 0, 0, 0, 0};
    for (int jj = lane; jj < 512; jj += 64) {
        float a = tanhf_fast(pooled[b * 512 + jj] * (1.0f / 2048.0f));
        #pragma unroll
        for (int g = 0; g < GG; g++) p[g] += a * fcW[g * 512 + jj];
    }
    #pragma unroll
    for (int g = 0; g < GG; g++)
        #pragma unroll
        for (int off = 32; off; off >>= 1) p[g] += __shfl_xor(p[g], off);
    if (lane == 0) {
        #pragma unroll
        for (int g = 0; g < GG; g++) out[b * GG + g] = p[g] + fcb[g];
    }
}

// ---------- launcher ----------
extern "C" void kernel_launch(void* const* d_in, const int* in_sizes, int n_in,
                              void* d_out, int out_size, void* d_ws, size_t ws_size,
                              hipStream_t stream)
{
    const int* tok = (const int*)d_in[0];
    const float* emb = (const float*)d_in[1];
    const float* Wih_f = (const float*)d_in[2];
    const float* Whh_f = (const float*)d_in[3];
    const float* bih_f = (const float*)d_in[4];
    const float* bhh_f = (const float*)d_in[5];
    const float* Wih_b = (const float*)d_in[6];
    const float* Whh_b = (const float*)d_in[7];
    const float* bih_b = (const float*)d_in[8];
    const float* bhh_b = (const float*)d_in[9];
    const float* fcW = (const float*)d_in[10];
    const float* fcb = (const float*)d_in[11];
    float* out = (float*)d_out;

    char* ws = (char*)d_ws;
    unsigned short* xq   = (unsigned short*)(ws);                       // 67,108,864 B
    unsigned short* Wp   = (unsigned short*)(ws + 67108864);            //    327,680 B
    unsigned short* Whp  = (unsigned short*)(ws + 67108864 + 327680);   //    262,144 B
    float* biasc         = (float*)(ws + 67108864 + 327680 + 262144);   //      2,048 B
    float* pooled        = (float*)(ws + 67108864 + 327680 + 262144 + 2048); // 65,536 B

    hipLaunchKernelGGL(k_pack, dim3(1154), dim3(256), 0, stream,
                       Wih_f, Whh_f, bih_f, bhh_f, Wih_b, Whh_b, bih_b, bhh_b,
                       Wp, Whp, biasc);
    hipLaunchKernelGGL(k_xproj, dim3(2048), dim3(1024), 0, stream,
                       tok, emb, Wp, biasc, xq);
    hipLaunchKernelGGL(k_rnn, dim3(4), dim3(512), 0, stream, xq, Whp, pooled);
    hipLaunchKernelGGL(k_head, dim3(32), dim3(64), 0, stream, pooled, fcW, fcb, out);
}

// Round 4
// 1413.354 us; speedup vs baseline: 1.2179x; 1.0066x over previous
//
#include <hip/hip_runtime.h>
#include <hip/hip_bf16.h>

// Problem constants
#define S_LEN 2048
#define BB 32
#define EE 300
#define HH 256
#define VV 50000
#define GG 5

typedef float f32x4 __attribute__((ext_vector_type(4)));
typedef __bf16 bf16x8 __attribute__((ext_vector_type(8)));
typedef int i32x4 __attribute__((ext_vector_type(4)));

// ---------- helpers ----------
__device__ __forceinline__ unsigned short f2bf(float f) {
    unsigned int u = __builtin_bit_cast(unsigned int, f);
    u = u + 0x7fffu + ((u >> 16) & 1u);   // RNE
    return (unsigned short)(u >> 16);
}
__device__ __forceinline__ float bflo(unsigned int w) {
    return __builtin_bit_cast(float, w << 16);
}
__device__ __forceinline__ float bfhi(unsigned int w) {
    return __builtin_bit_cast(float, w & 0xffff0000u);
}
__device__ __forceinline__ float tanhf_fast(float x) {
    // tanh(x) = 1 - 2/(e+1), e = exp2(x * 2*log2(e))  [3 VALU + 2 trans]
    float e = __builtin_amdgcn_exp2f(x * 2.8853900817779268f);
    float r = __builtin_amdgcn_rcpf(e + 1.0f);
    return __builtin_fmaf(-2.0f, r, 1.0f);
}
// pack two f32 -> dword of 2 bf16 (RNE), single instruction
__device__ __forceinline__ unsigned int cvt_pk_bf16(float lo, float hi) {
    unsigned int r;
    asm("v_cvt_pk_bf16_f32 %0, %1, %2" : "=v"(r) : "v"(lo), "v"(hi));
    return r;
}

// ---------- K0: pack weights into MFMA-fragment-friendly bf16 layouts ----------
// Wp  [dir][kb(10)][kg(4)][j(256)][i(8)]  <- W_ih[j][e], e = kb*32+kg*8+i (zero-pad e>=300)
// Whp [dir][kb(8) ][kg(4)][j(256)][i(8)]  <- W_hh[j][k], k = kb*32+kg*8+i
// biasc[dir*256+j] = b_ih[j] + b_hh[j]
__global__ void k_pack(const float* __restrict__ Wih_f, const float* __restrict__ Whh_f,
                       const float* __restrict__ bih_f, const float* __restrict__ bhh_f,
                       const float* __restrict__ Wih_b, const float* __restrict__ Whh_b,
                       const float* __restrict__ bih_b, const float* __restrict__ bhh_b,
                       unsigned short* __restrict__ Wp, unsigned short* __restrict__ Whp,
                       float* __restrict__ biasc)
{
    int idx = blockIdx.x * 256 + threadIdx.x;
    if (idx < 163840) {
        int i = idx & 7, j = (idx >> 3) & 255, kg = (idx >> 11) & 3, kbd = idx >> 13;
        int kb = kbd % 10, dir = kbd / 10;
        int e = kb * 32 + kg * 8 + i;
        const float* W = dir ? Wih_b : Wih_f;
        float v = (e < EE) ? W[j * EE + e] : 0.0f;
        Wp[idx] = f2bf(v);
    } else if (idx < 163840 + 131072) {
        int x = idx - 163840;
        int i = x & 7, j = (x >> 3) & 255, kg = (x >> 11) & 3, kbd = x >> 13;
        int kb = kbd & 7, dir = kbd >> 3;
        int k = kb * 32 + kg * 8 + i;
        const float* W = dir ? Whh_b : Whh_f;
        Whp[x] = f2bf(W[j * HH + k]);
    } else if (idx < 163840 + 131072 + 512) {
        int x = idx - (163840 + 131072);
        int j = x & 255, dir = x >> 8;
        biasc[x] = dir ? (bih_b[j] + bhh_b[j]) : (bih_f[j] + bhh_f[j]);
    }
}

// ---------- K2: embedding gather + input projection (transposed MFMA GEMM) ----------
// xq[s][dir][half][w4][lane][16 bf16]: [t(4)][r(4)] =
//   xproj^T(j = w4*64+t*16+(lane>>4)*4+r , b = half*16+(lane&15)) + bias[j]
__global__ __launch_bounds__(1024) void k_xproj(
    const int* __restrict__ tok, const float* __restrict__ emb,
    const unsigned short* __restrict__ Wp, const float* __restrict__ biasc,
    unsigned short* __restrict__ xq)
{
    __shared__ char xs[32 * 640];   // x[b][e(320)] bf16, XOR-swizzled rows
    int s = blockIdx.x;
    int tid = threadIdx.x;
    int lane = tid & 63, W16 = tid >> 6;

    #pragma unroll
    for (int k = 0; k < 5; k++) ((int*)xs)[tid + k * 1024] = 0;
    __syncthreads();

    {
        int b0 = W16 * 2;
        for (int rr = 0; rr < 2; rr++) {
            int b = b0 + rr;
            int t = tok[b * S_LEN + s];
            const float* row = emb + (size_t)t * EE;
            int xorv = (b & 7) << 4;
            #pragma unroll
            for (int c = 0; c < 5; c++) {
                int e = c * 64 + lane;
                if (e < EE) {
                    *(unsigned short*)(xs + b * 640 + ((2 * e) ^ xorv)) = f2bf(row[e]);
                }
            }
        }
    }
    __syncthreads();

    int dir = W16 >> 3, w = (W16 >> 1) & 3, half = W16 & 1;
    int l15 = lane & 15, kg = lane >> 4;
    f32x4 acc[4] = {};
    int brow = half * 16 + l15;
    int bxor = (brow & 7) << 4;
    const char* xrow = xs + brow * 640;

    #pragma unroll
    for (int kb = 0; kb < 10; kb++) {
        bf16x8 xb = *(const bf16x8*)(xrow + ((kb * 64 + kg * 16) ^ bxor));
        #pragma unroll
        for (int t = 0; t < 4; t++) {
            int j = w * 64 + t * 16 + l15;
            bf16x8 wa = *(const bf16x8*)(Wp + (size_t)(((dir * 10 + kb) * 4 + kg) * 256 + j) * 8);
            acc[t] = __builtin_amdgcn_mfma_f32_16x16x32_bf16(wa, xb, acc[t], 0, 0, 0);
        }
    }

    unsigned int words[8];
    #pragma unroll
    for (int t = 0; t < 4; t++) {
        float v[4];
        #pragma unroll
        for (int r = 0; r < 4; r++) {
            int j = w * 64 + t * 16 + kg * 4 + r;
            v[r] = acc[t][r] + biasc[dir * 256 + j];
        }
        words[t * 2 + 0] = cvt_pk_bf16(v[0], v[1]);
        words[t * 2 + 1] = cvt_pk_bf16(v[2], v[3]);
    }
    size_t base = (size_t)s * 32768 + (size_t)((dir * 2 + half) * 4 + w) * 2048 + (size_t)lane * 32;
    *(i32x4*)((char*)xq + base) = *(i32x4*)&words[0];
    *(i32x4*)((char*)xq + base + 16) = *(i32x4*)&words[4];
}

// ---------- K3: the sequential recurrence (4 persistent workgroups, 8 waves each) ----------
// block = (dir, batch-half). 8 waves -> 2 waves/SIMD for latency hiding.
// Wave w owns j in [w*32, w*32+32). W_hh fragments resident in VGPRs.
// h stored in LDS as k-blocked linear layout [kb(8)][kg(4)][b(16)][i(8)] bf16:
//   reads : per kb, the wave's 64 lanes cover contiguous [kb*1024, +1024) -> conflict-free
//   writes: per t,  the wave's 64 lanes cover contiguous [w*1024+t*512, +512) -> conflict-free
__global__ __launch_bounds__(512, 2) void k_rnn(
    const unsigned short* __restrict__ xq,
    const unsigned short* __restrict__ Whp,
    float* __restrict__ pooled)
{
    __shared__ char hb0[8192];
    __shared__ char hb1[8192];
    int bid = blockIdx.x;
    int dir = bid >> 1, half = bid & 1;
    int tid = threadIdx.x;
    int lane = tid & 63, w = tid >> 6;          // w in 0..7
    int l15 = lane & 15, kg = lane >> 4;

    // resident W_hh fragments: A-operand, lane holds W[j = w*32+t*16+l15][k = kb*32+kg*8 ..+8]
    bf16x8 wf[2][8];
    #pragma unroll
    for (int t = 0; t < 2; t++)
        #pragma unroll
        for (int kb = 0; kb < 8; kb++) {
            int j = w * 32 + t * 16 + l15;
            wf[t][kb] = *(const bf16x8*)(Whp + (size_t)(((dir * 8 + kb) * 4 + kg) * 256 + j) * 8);
        }

    // zero h buffer 0 (h_0 = 0): 512 threads x 16B = 8192B
    *(i32x4*)(&hb0[tid * 16]) = i32x4{0, 0, 0, 0};

    f32x4 pool[2] = {};

    // read cells: h[b=l15][k=kb*32+kg*8 ..+8] at kb*1024 + kg*256 + l15*16
    int rbase = kg * 256 + l15 * 16;
    // write cells: t -> w*1024 + (t*2 + (kg>>1))*256 + l15*16 + (kg&1)*8
    int woff[2];
    #pragma unroll
    for (int t = 0; t < 2; t++)
        woff[t] = w * 1024 + (t * 2 + (kg >> 1)) * 256 + l15 * 16 + (kg & 1) * 8;

    // xq record: 32B per (w4, lane); wave w reads 16B half (w&1)
    size_t lanebase = (size_t)((dir * 2 + half) * 4 + (w >> 1)) * 2048
                    + (size_t)lane * 32 + (size_t)(w & 1) * 16;
    ptrdiff_t sdelta = dir ? -(ptrdiff_t)32768 : (ptrdiff_t)32768;
    int s0 = dir ? (S_LEN - 1) : 0;

    const char* xqp = (const char*)xq + (size_t)s0 * 32768 + lanebase;
    i32x4 xn = *(const i32x4*)(xqp);
    xqp += sdelta;   // now points at step 1's data

    __syncthreads();

#define STEP(RB, WB, DO_PF)                                                          \
    {                                                                                \
        const char* rb = (RB) + rbase;                                               \
        bf16x8 hf[8];                                                                \
        _Pragma("unroll")                                                            \
        for (int kb = 0; kb < 8; kb++)                                               \
            hf[kb] = *(const bf16x8*)(rb + kb * 1024);                               \
        unsigned int wd[4];                                                          \
        *(i32x4*)&wd[0] = xn;                                                        \
        if (DO_PF) {                                                                 \
            xn = *(const i32x4*)(xqp);                                               \
            xqp += sdelta;                                                           \
        }                                                                            \
        f32x4 acc[2];                                                                \
        _Pragma("unroll")                                                            \
        for (int t = 0; t < 2; t++) {                                                \
            acc[t][0] = bflo(wd[t * 2 + 0]);                                         \
            acc[t][1] = bfhi(wd[t * 2 + 0]);                                         \
            acc[t][2] = bflo(wd[t * 2 + 1]);                                         \
            acc[t][3] = bfhi(wd[t * 2 + 1]);                                         \
        }                                                                            \
        _Pragma("unroll")                                                            \
        for (int kb = 0; kb < 8; kb++)                                               \
            _Pragma("unroll")                                                        \
            for (int t = 0; t < 2; t++)                                              \
                acc[t] = __builtin_amdgcn_mfma_f32_16x16x32_bf16(wf[t][kb], hf[kb],  \
                                                                 acc[t], 0, 0, 0);   \
        _Pragma("unroll")                                                            \
        for (int t = 0; t < 2; t++) {                                                \
            float h0 = tanhf_fast(acc[t][0]);                                        \
            float h1 = tanhf_fast(acc[t][1]);                                        \
            float h2 = tanhf_fast(acc[t][2]);                                        \
            float h3 = tanhf_fast(acc[t][3]);                                        \
            pool[t][0] += h0; pool[t][1] += h1;                                      \
            pool[t][2] += h2; pool[t][3] += h3;                                      \
            unsigned int lo = cvt_pk_bf16(h0, h1);                                   \
            unsigned int hi = cvt_pk_bf16(h2, h3);                                   \
            *(uint2*)((WB) + woff[t]) = make_uint2(lo, hi);                          \
        }                                                                            \
        asm volatile("s_waitcnt lgkmcnt(0)" ::: "memory");                           \
        __builtin_amdgcn_s_barrier();                                                \
    }

    // steps 0 .. S_LEN-3 (unrolled by 2, always prefetch: target step <= S_LEN-2)
    for (int i = 0; i < S_LEN - 2; i += 2) {
        STEP(hb0, hb1, 1)
        STEP(hb1, hb0, 1)
    }
    // step S_LEN-2: prefetch step S_LEN-1 (valid); step S_LEN-1: no prefetch
    STEP(hb0, hb1, 1)
    STEP(hb1, hb0, 0)
#undef STEP

    // write pooled sums (mean division happens in k_head)
    #pragma unroll
    for (int t = 0; t < 2; t++)
        #pragma unroll
        for (int r = 0; r < 4; r++) {
            int j = w * 32 + t * 16 + kg * 4 + r;
            int b = half * 16 + l15;
            pooled[b * 512 + dir * 256 + j] = pool[t][r];
        }
}

// ---------- K4: head: tanh(mean) @ fc_W^T + fc_b ----------
__global__ __launch_bounds__(64) void k_head(
    const float* __restrict__ pooled, const float* __restrict__ fcW,
    const float* __restrict__ fcb, float* __restrict__ out)
{
    int b = blockIdx.x;
    int lane = threadIdx.x;
    float p[GG] = {0, 0, 0, 0, 0};
    for (int jj = lane; jj < 512; jj += 64) {
        float a = tanhf_fast(pooled[b * 512 + jj] * (1.0f / 2048.0f));
        #pragma unroll
        for (int g = 0; g < GG; g++) p[g] += a * fcW[g * 512 + jj];
    }
    #pragma unroll
    for (int g = 0; g < GG; g++)
        #pragma unroll
        for (int off = 32; off; off >>= 1) p[g] += __shfl_xor(p[g], off);
    if (lane == 0) {
        #pragma unroll
        for (int g = 0; g < GG; g++) out[b * GG + g] = p[g] + fcb[g];
    }
}

// ---------- launcher ----------
extern "C" void kernel_launch(void* const* d_in, const int* in_sizes, int n_in,
                              void* d_out, int out_size, void* d_ws, size_t ws_size,
                              hipStream_t stream)
{
    const int* tok = (const int*)d_in[0];
    const float* emb = (const float*)d_in[1];
    const float* Wih_f = (const float*)d_in[2];
    const float* Whh_f = (const float*)d_in[3];
    const float* bih_f = (const float*)d_in[4];
    const float* bhh_f = (const float*)d_in[5];
    const float* Wih_b = (const float*)d_in[6];
    const float* Whh_b = (const float*)d_in[7];
    const float* bih_b = (const float*)d_in[8];
    const float* bhh_b = (const float*)d_in[9];
    const float* fcW = (const float*)d_in[10];
    const float* fcb = (const float*)d_in[11];
    float* out = (float*)d_out;

    char* ws = (char*)d_ws;
    unsigned short* xq   = (unsigned short*)(ws);                       // 67,108,864 B
    unsigned short* Wp   = (unsigned short*)(ws + 67108864);            //    327,680 B
    unsigned short* Whp  = (unsigned short*)(ws + 67108864 + 327680);   //    262,144 B
    float* biasc         = (float*)(ws + 67108864 + 327680 + 262144);   //      2,048 B
    float* pooled        = (float*)(ws + 67108864 + 327680 + 262144 + 2048); // 65,536 B

    hipLaunchKernelGGL(k_pack, dim3(1154), dim3(256), 0, stream,
                       Wih_f, Whh_f, bih_f, bhh_f, Wih_b, Whh_b, bih_b, bhh_b,
                       Wp, Whp, biasc);
    hipLaunchKernelGGL(k_xproj, dim3(2048), dim3(1024), 0, stream,
                       tok, emb, Wp, biasc, xq);
    hipLaunchKernelGGL(k_rnn, dim3(4), dim3(512), 0, stream, xq, Whp, pooled);
    hipLaunchKernelGGL(k_head, dim3(32), dim3(64), 0, stream, pooled, fcW, fcb, out);
}

// Round 5
// 1104.351 us; speedup vs baseline: 1.5587x; 1.2798x over previous
//
#include <hip/hip_runtime.h>
#include <hip/hip_bf16.h>

// Problem constants
#define S_LEN 2048
#define BB 32
#define EE 300
#define HH 256
#define VV 50000
#define GG 5

typedef float f32x4 __attribute__((ext_vector_type(4)));
typedef __bf16 bf16x8 __attribute__((ext_vector_type(8)));
typedef int i32x4 __attribute__((ext_vector_type(4)));

// ---------- helpers ----------
__device__ __forceinline__ unsigned short f2bf(float f) {
    unsigned int u = __builtin_bit_cast(unsigned int, f);
    u = u + 0x7fffu + ((u >> 16) & 1u);   // RNE
    return (unsigned short)(u >> 16);
}
__device__ __forceinline__ float bflo(unsigned int w) {
    return __builtin_bit_cast(float, w << 16);
}
__device__ __forceinline__ float bfhi(unsigned int w) {
    return __builtin_bit_cast(float, w & 0xffff0000u);
}
__device__ __forceinline__ float tanhf_fast(float x) {
    // tanh(x) = 1 - 2/(e+1), e = exp2(x * 2*log2(e))  [3 VALU + 2 trans]
    float e = __builtin_amdgcn_exp2f(x * 2.8853900817779268f);
    float r = __builtin_amdgcn_rcpf(e + 1.0f);
    return __builtin_fmaf(-2.0f, r, 1.0f);
}
// pack two f32 -> dword of 2 bf16 (RNE), single instruction
__device__ __forceinline__ unsigned int cvt_pk_bf16(float lo, float hi) {
    unsigned int r;
    asm("v_cvt_pk_bf16_f32 %0, %1, %2" : "=v"(r) : "v"(lo), "v"(hi));
    return r;
}

// ---------- K0: pack weights into MFMA-fragment-friendly bf16 layouts ----------
// Wp  [dir][kb(10)][kg(4)][j(256)][i(8)]  <- W_ih[j][e], e = kb*32+kg*8+i (zero-pad e>=300)
// Whp [dir][kb(8) ][kg(4)][j(256)][i(8)]  <- W_hh[j][k], k = kb*32+kg*8+i
// biasc[dir*256+j] = b_ih[j] + b_hh[j]
__global__ void k_pack(const float* __restrict__ Wih_f, const float* __restrict__ Whh_f,
                       const float* __restrict__ bih_f, const float* __restrict__ bhh_f,
                       const float* __restrict__ Wih_b, const float* __restrict__ Whh_b,
                       const float* __restrict__ bih_b, const float* __restrict__ bhh_b,
                       unsigned short* __restrict__ Wp, unsigned short* __restrict__ Whp,
                       float* __restrict__ biasc)
{
    int idx = blockIdx.x * 256 + threadIdx.x;
    if (idx < 163840) {
        int i = idx & 7, j = (idx >> 3) & 255, kg = (idx >> 11) & 3, kbd = idx >> 13;
        int kb = kbd % 10, dir = kbd / 10;
        int e = kb * 32 + kg * 8 + i;
        const float* W = dir ? Wih_b : Wih_f;
        float v = (e < EE) ? W[j * EE + e] : 0.0f;
        Wp[idx] = f2bf(v);
    } else if (idx < 163840 + 131072) {
        int x = idx - 163840;
        int i = x & 7, j = (x >> 3) & 255, kg = (x >> 11) & 3, kbd = x >> 13;
        int kb = kbd & 7, dir = kbd >> 3;
        int k = kb * 32 + kg * 8 + i;
        const float* W = dir ? Whh_b : Whh_f;
        Whp[x] = f2bf(W[j * HH + k]);
    } else if (idx < 163840 + 131072 + 512) {
        int x = idx - (163840 + 131072);
        int j = x & 255, dir = x >> 8;
        biasc[x] = dir ? (bih_b[j] + bhh_b[j]) : (bih_f[j] + bhh_f[j]);
    }
}

// ---------- K2: embedding gather + input projection (transposed MFMA GEMM) ----------
// xq[s][dir][half][w4][lane][16 bf16]: [t(4)][r(4)] =
//   xproj^T(j = w4*64+t*16+(lane>>4)*4+r , b = half*16+(lane&15)) + bias[j]
__global__ __launch_bounds__(1024) void k_xproj(
    const int* __restrict__ tok, const float* __restrict__ emb,
    const unsigned short* __restrict__ Wp, const float* __restrict__ biasc,
    unsigned short* __restrict__ xq)
{
    __shared__ char xs[32 * 640];   // x[b][e(320)] bf16, XOR-swizzled rows
    int s = blockIdx.x;
    int tid = threadIdx.x;
    int lane = tid & 63, W16 = tid >> 6;

    #pragma unroll
    for (int k = 0; k < 5; k++) ((int*)xs)[tid + k * 1024] = 0;
    __syncthreads();

    {
        int b0 = W16 * 2;
        for (int rr = 0; rr < 2; rr++) {
            int b = b0 + rr;
            int t = tok[b * S_LEN + s];
            const float* row = emb + (size_t)t * EE;
            int xorv = (b & 7) << 4;
            #pragma unroll
            for (int c = 0; c < 5; c++) {
                int e = c * 64 + lane;
                if (e < EE) {
                    *(unsigned short*)(xs + b * 640 + ((2 * e) ^ xorv)) = f2bf(row[e]);
                }
            }
        }
    }
    __syncthreads();

    int dir = W16 >> 3, w = (W16 >> 1) & 3, half = W16 & 1;
    int l15 = lane & 15, kg = lane >> 4;
    f32x4 acc[4] = {};
    int brow = half * 16 + l15;
    int bxor = (brow & 7) << 4;
    const char* xrow = xs + brow * 640;

    #pragma unroll
    for (int kb = 0; kb < 10; kb++) {
        bf16x8 xb = *(const bf16x8*)(xrow + ((kb * 64 + kg * 16) ^ bxor));
        #pragma unroll
        for (int t = 0; t < 4; t++) {
            int j = w * 64 + t * 16 + l15;
            bf16x8 wa = *(const bf16x8*)(Wp + (size_t)(((dir * 10 + kb) * 4 + kg) * 256 + j) * 8);
            acc[t] = __builtin_amdgcn_mfma_f32_16x16x32_bf16(wa, xb, acc[t], 0, 0, 0);
        }
    }

    unsigned int words[8];
    #pragma unroll
    for (int t = 0; t < 4; t++) {
        float v[4];
        #pragma unroll
        for (int r = 0; r < 4; r++) {
            int j = w * 64 + t * 16 + kg * 4 + r;
            v[r] = acc[t][r] + biasc[dir * 256 + j];
        }
        words[t * 2 + 0] = cvt_pk_bf16(v[0], v[1]);
        words[t * 2 + 1] = cvt_pk_bf16(v[2], v[3]);
    }
    size_t base = (size_t)s * 32768 + (size_t)((dir * 2 + half) * 4 + w) * 2048 + (size_t)lane * 32;
    *(i32x4*)((char*)xq + base) = *(i32x4*)&words[0];
    *(i32x4*)((char*)xq + base + 16) = *(i32x4*)&words[4];
}

// ---------- K3: the sequential recurrence (4 persistent workgroups, 16 waves each) ----------
// block = (dir, batch-half). 16 waves -> 4 waves/SIMD for latency hiding.
// Wave w owns j in [w*16, w*16+16) (one 8-deep MFMA chain). W_hh fragments in VGPRs.
// h in LDS, k-blocked linear layout [kb(8)][kg(4)][b(16)][i(8)] bf16 (conflict-free).
// Latency schedule: acc starts at 0, xproj added AFTER the MFMAs (vmcnt wait off the
// MFMA critical path); xq prefetched 2 steps ahead; pool accumulated after the barrier.
__global__ __launch_bounds__(1024, 4) void k_rnn(
    const unsigned short* __restrict__ xq,
    const unsigned short* __restrict__ Whp,
    float* __restrict__ pooled)
{
    __shared__ char hb0[8192];
    __shared__ char hb1[8192];
    int bid = blockIdx.x;
    int dir = bid >> 1, half = bid & 1;
    int tid = threadIdx.x;
    int lane = tid & 63, w = tid >> 6;          // w in 0..15
    int l15 = lane & 15, kg = lane >> 4;

    // resident W_hh fragments: A-operand, lane holds W[j = w*16+l15][k = kb*32+kg*8 ..+8]
    bf16x8 wf[8];
    #pragma unroll
    for (int kb = 0; kb < 8; kb++) {
        int j = w * 16 + l15;
        wf[kb] = *(const bf16x8*)(Whp + (size_t)(((dir * 8 + kb) * 4 + kg) * 256 + j) * 8);
    }

    // zero h buffer 0 (h_0 = 0): 1024 threads x 8B = 8192B
    *(uint2*)(&hb0[tid * 8]) = make_uint2(0, 0);

    f32x4 pool = {};

    // read cells: h[b=l15][k=kb*32+kg*8 ..+8] at kb*1024 + kg*256 + l15*16
    int rbase = kg * 256 + l15 * 16;
    // write cell: j=w*16+kg*4+r -> (w>>1)*1024 + ((w&1)*2+(kg>>1))*256 + l15*16 + (kg&1)*8
    int woff = (w >> 1) * 1024 + ((w & 1) * 2 + (kg >> 1)) * 256 + l15 * 16 + (kg & 1) * 8;

    // xq record: 32B per (w4=w>>2, lane); wave w reads the 8B quarter (w&3)
    size_t lanebase = (size_t)((dir * 2 + half) * 4 + (w >> 2)) * 2048
                    + (size_t)lane * 32 + (size_t)(w & 3) * 8;
    ptrdiff_t sdelta = dir ? -(ptrdiff_t)32768 : (ptrdiff_t)32768;
    int s0 = dir ? (S_LEN - 1) : 0;

    const char* xqp = (const char*)xq + (size_t)s0 * 32768 + lanebase;
    uint2 xc0 = *(const uint2*)(xqp); xqp += sdelta;   // step 0
    uint2 xc1 = *(const uint2*)(xqp); xqp += sdelta;   // step 1; xqp -> step 2

    __syncthreads();

#define STEP(RB, WB, XC, DO_PF)                                                      \
    {                                                                                \
        const char* rb = (RB) + rbase;                                               \
        bf16x8 hf[8];                                                                \
        _Pragma("unroll")                                                            \
        for (int kb = 0; kb < 8; kb++)                                               \
            hf[kb] = *(const bf16x8*)(rb + kb * 1024);                               \
        f32x4 acc = {0.0f, 0.0f, 0.0f, 0.0f};                                        \
        _Pragma("unroll")                                                            \
        for (int kb = 0; kb < 8; kb++)                                               \
            acc = __builtin_amdgcn_mfma_f32_16x16x32_bf16(wf[kb], hf[kb],            \
                                                          acc, 0, 0, 0);             \
        float xp0 = bflo(XC.x), xp1 = bfhi(XC.x);                                    \
        float xp2 = bflo(XC.y), xp3 = bfhi(XC.y);                                    \
        if (DO_PF) { XC = *(const uint2*)(xqp); xqp += sdelta; }                     \
        float h0 = tanhf_fast(acc[0] + xp0);                                         \
        float h1 = tanhf_fast(acc[1] + xp1);                                         \
        float h2 = tanhf_fast(acc[2] + xp2);                                         \
        float h3 = tanhf_fast(acc[3] + xp3);                                         \
        unsigned int lo = cvt_pk_bf16(h0, h1);                                       \
        unsigned int hi = cvt_pk_bf16(h2, h3);                                       \
        *(uint2*)((WB) + woff) = make_uint2(lo, hi);                                 \
        asm volatile("s_waitcnt lgkmcnt(0)" ::: "memory");                           \
        __builtin_amdgcn_s_barrier();                                                \
        pool[0] += h0; pool[1] += h1; pool[2] += h2; pool[3] += h3;                  \
    }

    // steps 0 .. S_LEN-5 (prefetch target i+2 always valid)
    for (int i = 0; i < S_LEN - 4; i += 2) {
        STEP(hb0, hb1, xc0, 1)
        STEP(hb1, hb0, xc1, 1)
    }
    // steps S_LEN-4 .. S_LEN-1
    STEP(hb0, hb1, xc0, 1)   // prefetches S_LEN-2
    STEP(hb1, hb0, xc1, 1)   // prefetches S_LEN-1
    STEP(hb0, hb1, xc0, 0)
    STEP(hb1, hb0, xc1, 0)
#undef STEP

    // write pooled sums (mean division happens in k_head)
    #pragma unroll
    for (int r = 0; r < 4; r++) {
        int j = w * 16 + kg * 4 + r;
        int b = half * 16 + l15;
        pooled[b * 512 + dir * 256 + j] = pool[r];
    }
}

// ---------- K4: head: tanh(mean) @ fc_W^T + fc_b ----------
__global__ __launch_bounds__(64) void k_head(
    const float* __restrict__ pooled, const float* __restrict__ fcW,
    const float* __restrict__ fcb, float* __restrict__ out)
{
    int b = blockIdx.x;
    int lane = threadIdx.x;
    float p[GG] = {0, 0, 0, 0, 0};
    for (int jj = lane; jj < 512; jj += 64) {
        float a = tanhf_fast(pooled[b * 512 + jj] * (1.0f / 2048.0f));
        #pragma unroll
        for (int g = 0; g < GG; g++) p[g] += a * fcW[g * 512 + jj];
    }
    #pragma unroll
    for (int g = 0; g < GG; g++)
        #pragma unroll
        for (int off = 32; off; off >>= 1) p[g] += __shfl_xor(p[g], off);
    if (lane == 0) {
        #pragma unroll
        for (int g = 0; g < GG; g++) out[b * GG + g] = p[g] + fcb[g];
    }
}

// ---------- launcher ----------
extern "C" void kernel_launch(void* const* d_in, const int* in_sizes, int n_in,
                              void* d_out, int out_size, void* d_ws, size_t ws_size,
                              hipStream_t stream)
{
    const int* tok = (const int*)d_in[0];
    const float* emb = (const float*)d_in[1];
    const float* Wih_f = (const float*)d_in[2];
    const float* Whh_f = (const float*)d_in[3];
    const float* bih_f = (const float*)d_in[4];
    const float* bhh_f = (const float*)d_in[5];
    const float* Wih_b = (const float*)d_in[6];
    const float* Whh_b = (const float*)d_in[7];
    const float* bih_b = (const float*)d_in[8];
    const float* bhh_b = (const float*)d_in[9];
    const float* fcW = (const float*)d_in[10];
    const float* fcb = (const float*)d_in[11];
    float* out = (float*)d_out;

    char* ws = (char*)d_ws;
    unsigned short* xq   = (unsigned short*)(ws);                       // 67,108,864 B
    unsigned short* Wp   = (unsigned short*)(ws + 67108864);            //    327,680 B
    unsigned short* Whp  = (unsigned short*)(ws + 67108864 + 327680);   //    262,144 B
    float* biasc         = (float*)(ws + 67108864 + 327680 + 262144);   //      2,048 B
    float* pooled        = (float*)(ws + 67108864 + 327680 + 262144 + 2048); // 65,536 B

    hipLaunchKernelGGL(k_pack, dim3(1154), dim3(256), 0, stream,
                       Wih_f, Whh_f, bih_f, bhh_f, Wih_b, Whh_b, bih_b, bhh_b,
                       Wp, Whp, biasc);
    hipLaunchKernelGGL(k_xproj, dim3(2048), dim3(1024), 0, stream,
                       tok, emb, Wp, biasc, xq);
    hipLaunchKernelGGL(k_rnn, dim3(4), dim3(1024), 0, stream, xq, Whp, pooled);
    hipLaunchKernelGGL(k_head, dim3(32), dim3(64), 0, stream, pooled, fcW, fcb, out);
}

// Round 6
// 1036.960 us; speedup vs baseline: 1.6599x; 1.0650x over previous
//
#include <hip/hip_runtime.h>
#include <hip/hip_bf16.h>

// Problem constants
#define S_LEN 2048
#define BB 32
#define EE 300
#define HH 256
#define VV 50000
#define GG 5

// 2*log2(e): folded into W_ih/W_hh/biases at pack time so tanh needs no input scaling
#define K2LOG2E 2.8853900817779268f

typedef float f32x4 __attribute__((ext_vector_type(4)));
typedef __bf16 bf16x8 __attribute__((ext_vector_type(8)));
typedef int i32x4 __attribute__((ext_vector_type(4)));

// ---------- helpers ----------
__device__ __forceinline__ unsigned short f2bf(float f) {
    unsigned int u = __builtin_bit_cast(unsigned int, f);
    u = u + 0x7fffu + ((u >> 16) & 1u);   // RNE
    return (unsigned short)(u >> 16);
}
__device__ __forceinline__ float bflo(unsigned int w) {
    return __builtin_bit_cast(float, w << 16);
}
__device__ __forceinline__ float bfhi(unsigned int w) {
    return __builtin_bit_cast(float, w & 0xffff0000u);
}
// tanh for PRE-SCALED input (x already multiplied by 2*log2(e)): 2 VALU + 2 trans
__device__ __forceinline__ float tanh_pre(float xs) {
    float e = __builtin_amdgcn_exp2f(xs);
    float r = __builtin_amdgcn_rcpf(e + 1.0f);
    return __builtin_fmaf(-2.0f, r, 1.0f);
}
// tanh for unscaled input (head kernel only)
__device__ __forceinline__ float tanhf_fast(float x) {
    return tanh_pre(x * K2LOG2E);
}
// pack two f32 -> dword of 2 bf16 (RNE), single instruction
__device__ __forceinline__ unsigned int cvt_pk_bf16(float lo, float hi) {
    unsigned int r;
    asm("v_cvt_pk_bf16_f32 %0, %1, %2" : "=v"(r) : "v"(lo), "v"(hi));
    return r;
}

// ---------- K0: pack weights into MFMA-fragment-friendly bf16 layouts ----------
// All recurrence-path weights/biases are pre-scaled by 2*log2(e).
// Wp  [dir][kb(10)][kg(4)][j(256)][i(8)]  <- K2*W_ih[j][e], e = kb*32+kg*8+i (zero-pad e>=300)
// Whp [dir][kb(8) ][kg(4)][j(256)][i(8)]  <- K2*W_hh[j][k], k = kb*32+kg*8+i
// biasc[dir*256+j] = K2*(b_ih[j] + b_hh[j])
__global__ void k_pack(const float* __restrict__ Wih_f, const float* __restrict__ Whh_f,
                       const float* __restrict__ bih_f, const float* __restrict__ bhh_f,
                       const float* __restrict__ Wih_b, const float* __restrict__ Whh_b,
                       const float* __restrict__ bih_b, const float* __restrict__ bhh_b,
                       unsigned short* __restrict__ Wp, unsigned short* __restrict__ Whp,
                       float* __restrict__ biasc)
{
    int idx = blockIdx.x * 256 + threadIdx.x;
    if (idx < 163840) {
        int i = idx & 7, j = (idx >> 3) & 255, kg = (idx >> 11) & 3, kbd = idx >> 13;
        int kb = kbd % 10, dir = kbd / 10;
        int e = kb * 32 + kg * 8 + i;
        const float* W = dir ? Wih_b : Wih_f;
        float v = (e < EE) ? W[j * EE + e] * K2LOG2E : 0.0f;
        Wp[idx] = f2bf(v);
    } else if (idx < 163840 + 131072) {
        int x = idx - 163840;
        int i = x & 7, j = (x >> 3) & 255, kg = (x >> 11) & 3, kbd = x >> 13;
        int kb = kbd & 7, dir = kbd >> 3;
        int k = kb * 32 + kg * 8 + i;
        const float* W = dir ? Whh_b : Whh_f;
        Whp[x] = f2bf(W[j * HH + k] * K2LOG2E);
    } else if (idx < 163840 + 131072 + 512) {
        int x = idx - (163840 + 131072);
        int j = x & 255, dir = x >> 8;
        biasc[x] = (dir ? (bih_b[j] + bhh_b[j]) : (bih_f[j] + bhh_f[j])) * K2LOG2E;
    }
}

// ---------- K2: embedding gather + input projection (transposed MFMA GEMM) ----------
// xq[s][dir][half][w4][lane][16 bf16]: [t(4)][r(4)] =
//   K2 * (xproj^T(j = w4*64+t*16+(lane>>4)*4+r , b = half*16+(lane&15)) + bias[j])
__global__ __launch_bounds__(1024) void k_xproj(
    const int* __restrict__ tok, const float* __restrict__ emb,
    const unsigned short* __restrict__ Wp, const float* __restrict__ biasc,
    unsigned short* __restrict__ xq)
{
    __shared__ char xs[32 * 640];   // x[b][e(320)] bf16, XOR-swizzled rows
    int s = blockIdx.x;
    int tid = threadIdx.x;
    int lane = tid & 63, W16 = tid >> 6;

    #pragma unroll
    for (int k = 0; k < 5; k++) ((int*)xs)[tid + k * 1024] = 0;
    __syncthreads();

    {
        int b0 = W16 * 2;
        for (int rr = 0; rr < 2; rr++) {
            int b = b0 + rr;
            int t = tok[b * S_LEN + s];
            const float* row = emb + (size_t)t * EE;
            int xorv = (b & 7) << 4;
            #pragma unroll
            for (int c = 0; c < 5; c++) {
                int e = c * 64 + lane;
                if (e < EE) {
                    *(unsigned short*)(xs + b * 640 + ((2 * e) ^ xorv)) = f2bf(row[e]);
                }
            }
        }
    }
    __syncthreads();

    int dir = W16 >> 3, w = (W16 >> 1) & 3, half = W16 & 1;
    int l15 = lane & 15, kg = lane >> 4;
    f32x4 acc[4] = {};
    int brow = half * 16 + l15;
    int bxor = (brow & 7) << 4;
    const char* xrow = xs + brow * 640;

    #pragma unroll
    for (int kb = 0; kb < 10; kb++) {
        bf16x8 xb = *(const bf16x8*)(xrow + ((kb * 64 + kg * 16) ^ bxor));
        #pragma unroll
        for (int t = 0; t < 4; t++) {
            int j = w * 64 + t * 16 + l15;
            bf16x8 wa = *(const bf16x8*)(Wp + (size_t)(((dir * 10 + kb) * 4 + kg) * 256 + j) * 8);
            acc[t] = __builtin_amdgcn_mfma_f32_16x16x32_bf16(wa, xb, acc[t], 0, 0, 0);
        }
    }

    unsigned int words[8];
    #pragma unroll
    for (int t = 0; t < 4; t++) {
        float v[4];
        #pragma unroll
        for (int r = 0; r < 4; r++) {
            int j = w * 64 + t * 16 + kg * 4 + r;
            v[r] = acc[t][r] + biasc[dir * 256 + j];
        }
        words[t * 2 + 0] = cvt_pk_bf16(v[0], v[1]);
        words[t * 2 + 1] = cvt_pk_bf16(v[2], v[3]);
    }
    size_t base = (size_t)s * 32768 + (size_t)((dir * 2 + half) * 4 + w) * 2048 + (size_t)lane * 32;
    *(i32x4*)((char*)xq + base) = *(i32x4*)&words[0];
    *(i32x4*)((char*)xq + base + 16) = *(i32x4*)&words[4];
}

// ---------- K3: the sequential recurrence (4 persistent workgroups, 16 waves each) ----------
// block = (dir, batch-half). 16 waves -> 4 waves/SIMD. Wave w owns j in [w*16, w*16+16).
// W_hh (pre-scaled) resident in VGPRs. h in LDS, k-blocked [kb(8)][kg(4)][b(16)][i(8)] bf16
// (conflict-free by construction). Instruction-diet schedule:
//   - xproj unpacked DIRECTLY into the MFMA C-init (no zero-movs, no post-adds);
//     vmcnt wait is 2-steps-slack deep so it's free.
//   - tanh on pre-scaled input: exp2, add, rcp, fma (no mul).
//   - xq addressed via uniform base + 32-bit offset.
__global__ __launch_bounds__(1024, 4) void k_rnn(
    const unsigned short* __restrict__ xq,
    const unsigned short* __restrict__ Whp,
    float* __restrict__ pooled)
{
    __shared__ char hb0[8192];
    __shared__ char hb1[8192];
    int bid = blockIdx.x;
    int dir = bid >> 1, half = bid & 1;
    int tid = threadIdx.x;
    int lane = tid & 63, w = tid >> 6;          // w in 0..15
    int l15 = lane & 15, kg = lane >> 4;

    // resident W_hh fragments: A-operand, lane holds W[j = w*16+l15][k = kb*32+kg*8 ..+8]
    bf16x8 wf[8];
    #pragma unroll
    for (int kb = 0; kb < 8; kb++) {
        int j = w * 16 + l15;
        wf[kb] = *(const bf16x8*)(Whp + (size_t)(((dir * 8 + kb) * 4 + kg) * 256 + j) * 8);
    }

    // zero h buffer 0 (h_0 = 0): 1024 threads x 8B = 8192B
    *(uint2*)(&hb0[tid * 8]) = make_uint2(0, 0);

    f32x4 pool = {};

    // read cells: h[b=l15][k=kb*32+kg*8 ..+8] at kb*1024 + kg*256 + l15*16
    int rbase = kg * 256 + l15 * 16;
    // write cell: j=w*16+kg*4+r -> (w>>1)*1024 + ((w&1)*2+(kg>>1))*256 + l15*16 + (kg&1)*8
    int woff = (w >> 1) * 1024 + ((w & 1) * 2 + (kg >> 1)) * 256 + l15 * 16 + (kg & 1) * 8;

    // xq record: 32B per (w4=w>>2, lane); wave w reads the 8B quarter (w&3)
    int lanebase = ((dir * 2 + half) * 4 + (w >> 2)) * 2048 + lane * 32 + (w & 3) * 8;
    int sdelta = dir ? -32768 : 32768;
    int s0 = dir ? (S_LEN - 1) : 0;

    const char* xqb = (const char*)xq;   // uniform base (SGPR) + 32-bit lane offset
    int xoff = s0 * 32768 + lanebase;
    uint2 xc0 = *(const uint2*)(xqb + xoff); xoff += sdelta;   // step 0
    uint2 xc1 = *(const uint2*)(xqb + xoff); xoff += sdelta;   // step 1; xoff -> step 2

    __syncthreads();

#define STEP(RB, WB, XC, DO_PF)                                                      \
    {                                                                                \
        const char* rb = (RB) + rbase;                                               \
        bf16x8 hf[8];                                                                \
        _Pragma("unroll")                                                            \
        for (int kb = 0; kb < 8; kb++)                                               \
            hf[kb] = *(const bf16x8*)(rb + kb * 1024);                               \
        f32x4 acc;                                                                   \
        acc[0] = bflo(XC.x);                                                         \
        acc[1] = bfhi(XC.x);                                                         \
        acc[2] = bflo(XC.y);                                                         \
        acc[3] = bfhi(XC.y);                                                         \
        if (DO_PF) { XC = *(const uint2*)(xqb + xoff); xoff += sdelta; }             \
        _Pragma("unroll")                                                            \
        for (int kb = 0; kb < 8; kb++)                                               \
            acc = __builtin_amdgcn_mfma_f32_16x16x32_bf16(wf[kb], hf[kb],            \
                                                          acc, 0, 0, 0);             \
        float h0 = tanh_pre(acc[0]);                                                 \
        float h1 = tanh_pre(acc[1]);                                                 \
        float h2 = tanh_pre(acc[2]);                                                 \
        float h3 = tanh_pre(acc[3]);                                                 \
        unsigned int lo = cvt_pk_bf16(h0, h1);                                       \
        unsigned int hi = cvt_pk_bf16(h2, h3);                                       \
        *(uint2*)((WB) + woff) = make_uint2(lo, hi);                                 \
        asm volatile("s_waitcnt lgkmcnt(0)" ::: "memory");                           \
        __builtin_amdgcn_s_barrier();                                                \
        pool[0] += h0; pool[1] += h1; pool[2] += h2; pool[3] += h3;                  \
    }

    // steps 0 .. S_LEN-5 (prefetch target i+2 always valid)
    for (int i = 0; i < S_LEN - 4; i += 2) {
        STEP(hb0, hb1, xc0, 1)
        STEP(hb1, hb0, xc1, 1)
    }
    // steps S_LEN-4 .. S_LEN-1
    STEP(hb0, hb1, xc0, 1)   // prefetches S_LEN-2
    STEP(hb1, hb0, xc1, 1)   // prefetches S_LEN-1
    STEP(hb0, hb1, xc0, 0)
    STEP(hb1, hb0, xc1, 0)
#undef STEP

    // write pooled sums (mean division happens in k_head)
    #pragma unroll
    for (int r = 0; r < 4; r++) {
        int j = w * 16 + kg * 4 + r;
        int b = half * 16 + l15;
        pooled[b * 512 + dir * 256 + j] = pool[r];
    }
}

// ---------- K4: head: tanh(mean) @ fc_W^T + fc_b ----------
__global__ __launch_bounds__(64) void k_head(
    const float* __restrict__ pooled, const float* __restrict__ fcW,
    const float* __restrict__ fcb, float* __restrict__ out)
{
    int b = blockIdx.x;
    int lane = threadIdx.x;
    float p[GG] = {0, 0, 0, 0, 0};
    for (int jj = lane; jj < 512; jj += 64) {
        float a = tanhf_fast(pooled[b * 512 + jj] * (1.0f / 2048.0f));
        #pragma unroll
        for (int g = 0; g < GG; g++) p[g] += a * fcW[g * 512 + jj];
    }
    #pragma unroll
    for (int g = 0; g < GG; g++)
        #pragma unroll
        for (int off = 32; off; off >>= 1) p[g] += __shfl_xor(p[g], off);
    if (lane == 0) {
        #pragma unroll
        for (int g = 0; g < GG; g++) out[b * GG + g] = p[g] + fcb[g];
    }
}

// ---------- launcher ----------
extern "C" void kernel_launch(void* const* d_in, const int* in_sizes, int n_in,
                              void* d_out, int out_size, void* d_ws, size_t ws_size,
                              hipStream_t stream)
{
    const int* tok = (const int*)d_in[0];
    const float* emb = (const float*)d_in[1];
    const float* Wih_f = (const float*)d_in[2];
    const float* Whh_f = (const float*)d_in[3];
    const float* bih_f = (const float*)d_in[4];
    const float* bhh_f = (const float*)d_in[5];
    const float* Wih_b = (const float*)d_in[6];
    const float* Whh_b = (const float*)d_in[7];
    const float* bih_b = (const float*)d_in[8];
    const float* bhh_b = (const float*)d_in[9];
    const float* fcW = (const float*)d_in[10];
    const float* fcb = (const float*)d_in[11];
    float* out = (float*)d_out;

    char* ws = (char*)d_ws;
    unsigned short* xq   = (unsigned short*)(ws);                       // 67,108,864 B
    unsigned short* Wp   = (unsigned short*)(ws + 67108864);            //    327,680 B
    unsigned short* Whp  = (unsigned short*)(ws + 67108864 + 327680);   //    262,144 B
    float* biasc         = (float*)(ws + 67108864 + 327680 + 262144);   //      2,048 B
    float* pooled        = (float*)(ws + 67108864 + 327680 + 262144 + 2048); // 65,536 B

    hipLaunchKernelGGL(k_pack, dim3(1154), dim3(256), 0, stream,
                       Wih_f, Whh_f, bih_f, bhh_f, Wih_b, Whh_b, bih_b, bhh_b,
                       Wp, Whp, biasc);
    hipLaunchKernelGGL(k_xproj, dim3(2048), dim3(1024), 0, stream,
                       tok, emb, Wp, biasc, xq);
    hipLaunchKernelGGL(k_rnn, dim3(4), dim3(1024), 0, stream, xq, Whp, pooled);
    hipLaunchKernelGGL(k_head, dim3(32), dim3(64), 0, stream, pooled, fcW, fcb, out);
}